// Round 5
// baseline (16373.933 us; speedup 1.0000x reference)
//
#include <hip/hip_runtime.h>
#include <hip/hip_bf16.h>
#include <math.h>

// BiLSTM-CRF forward: B=32, T=512, E=512, H=256 (per dir), 4H=1024, K=12
// Inputs: fp32 (+ int32 sentence). Outputs: **fp32** in d_out:
//   [0,1024)      path_score [32][32]
//   [1024,17408)  best_path  [32][512] (tag values as fp32)
// R5: R4's all-VALU pipeline unchanged; ONLY output dtype bf16 -> fp32.

__device__ __forceinline__ float sigm(float x) { return 1.0f / (1.0f + expf(-x)); }

// ---------------------------------------------------------------------------
// Kernel 1: xg[m=(b,t)][n] = embed[sent[m]] . w_ih[n] + bias[n]
// M=16384, N=2048 (n<1024 fwd row n, else bwd row n-1024), K=512.
// 64x64 tile per WG, plain fp32 LDS tiling, 4x4 outputs/thread.
// ---------------------------------------------------------------------------
__global__ __launch_bounds__(256) void xg_simple(
    const int* __restrict__ sent, const float* __restrict__ embed,
    const float* __restrict__ wf, const float* __restrict__ wb,
    const float* __restrict__ bf, const float* __restrict__ bb,
    float* __restrict__ xg)
{
  __shared__ float As[64][33], Bs[64][33];
  __shared__ int toks[64];
  const int tid = threadIdx.x;
  const int m0 = blockIdx.x * 64, n0 = blockIdx.y * 64;
  if (tid < 64) toks[tid] = sent[m0 + tid];
  float acc[4][4];
#pragma unroll
  for (int im = 0; im < 4; im++)
#pragma unroll
    for (int in_ = 0; in_ < 4; in_++) acc[im][in_] = 0.0f;
  __syncthreads();

  const int ty = tid >> 4, tx = tid & 15;
  for (int k0 = 0; k0 < 512; k0 += 32) {
#pragma unroll
    for (int i = 0; i < 8; i++) {
      int idx = tid * 8 + i;          // 0..2047, thread-contiguous 8-elem runs
      int r = idx >> 5, kk = idx & 31;
      As[r][kk] = embed[(size_t)toks[r] * 512 + k0 + kk];
      int n = n0 + r;
      const float* wsrc = (n < 1024) ? (wf + (size_t)n * 512)
                                     : (wb + (size_t)(n - 1024) * 512);
      Bs[r][kk] = wsrc[k0 + kk];
    }
    __syncthreads();
#pragma unroll 8
    for (int k = 0; k < 32; k++) {
      float a[4], b[4];
#pragma unroll
      for (int im = 0; im < 4; im++) a[im] = As[ty * 4 + im][k];
#pragma unroll
      for (int in_ = 0; in_ < 4; in_++) b[in_] = Bs[tx * 4 + in_][k];
#pragma unroll
      for (int im = 0; im < 4; im++)
#pragma unroll
        for (int in_ = 0; in_ < 4; in_++)
          acc[im][in_] += a[im] * b[in_];
    }
    __syncthreads();
  }

#pragma unroll
  for (int in_ = 0; in_ < 4; in_++) {
    int n = n0 + tx * 4 + in_;
    float bv = (n < 1024) ? bf[n] : bb[n - 1024];
#pragma unroll
    for (int im = 0; im < 4; im++) {
      int m = m0 + ty * 4 + im;
      xg[(size_t)m * 2048 + n] = acc[im][in_] + bv;
    }
  }
}

// ---------------------------------------------------------------------------
// Kernel 2: LSTM recurrences, one WG per (dir, batch) — fully independent.
// 256 threads = 256 hidden units; thread u computes all 4 gates for unit u,
// c-state lives in a register, h_prev broadcast via LDS. w_hh streamed (L2).
// ---------------------------------------------------------------------------
__global__ __launch_bounds__(256) void lstm_simple(
    const float* __restrict__ xg,
    const float* __restrict__ whh_f, const float* __restrict__ whh_b,
    const float* __restrict__ h0, const float* __restrict__ c0,
    float* __restrict__ h_seq)     // [32][512][512]: cols 0-255 fwd, 256-511 bwd
{
  const int blk = blockIdx.x;
  const int d = blk >> 5, b = blk & 31;
  const int u = threadIdx.x;
  const float* __restrict__ whh = d ? whh_b : whh_f;

  __shared__ float hsh[256];
  float c = c0[d * 8192 + b * 256 + u];
  hsh[u] = h0[d * 8192 + b * 256 + u];
  const float* w0 = whh + (size_t)(0 * 256 + u) * 256;
  const float* w1 = whh + (size_t)(1 * 256 + u) * 256;
  const float* w2 = whh + (size_t)(2 * 256 + u) * 256;
  const float* w3 = whh + (size_t)(3 * 256 + u) * 256;
  __syncthreads();

  for (int s = 0; s < 512; s++) {
    const int t = d ? (511 - s) : s;
    const float* xr = xg + ((size_t)(b * 512 + t)) * 2048 + d * 1024 + u;
    float a0 = xr[0], a1 = xr[256], a2 = xr[512], a3 = xr[768];
#pragma unroll 4
    for (int k4 = 0; k4 < 256; k4 += 4) {
      float4 hv = *(const float4*)&hsh[k4];
      float4 v0 = *(const float4*)&w0[k4];
      float4 v1 = *(const float4*)&w1[k4];
      float4 v2 = *(const float4*)&w2[k4];
      float4 v3 = *(const float4*)&w3[k4];
      a0 += hv.x * v0.x + hv.y * v0.y + hv.z * v0.z + hv.w * v0.w;
      a1 += hv.x * v1.x + hv.y * v1.y + hv.z * v1.z + hv.w * v1.w;
      a2 += hv.x * v2.x + hv.y * v2.y + hv.z * v2.z + hv.w * v2.w;
      a3 += hv.x * v3.x + hv.y * v3.y + hv.z * v3.z + hv.w * v3.w;
    }
    float iv = sigm(a0), fg = sigm(a1), gv = tanhf(a2), ov = sigm(a3);
    c = fg * c + iv * gv;
    float h = ov * tanhf(c);
    __syncthreads();                 // all dot-reads of old hsh done
    hsh[u] = h;
    h_seq[((size_t)(b * 512 + t)) * 512 + d * 256 + u] = h;
    __syncthreads();                 // new hsh visible before next dot
  }
}

// ---------------------------------------------------------------------------
// Kernel 3: feats[m][k] = h_seq[m][:] . W_out[k][:] + b_out[k]   (fp32)
// one wave per row m = b*512+t
// ---------------------------------------------------------------------------
__global__ __launch_bounds__(256) void feats_k(
    const float* __restrict__ h_seq, const float* __restrict__ W_out,
    const float* __restrict__ b_out, float* __restrict__ feats)
{
  int m = blockIdx.x * 4 + (threadIdx.x >> 6);
  int lane = threadIdx.x & 63;
  const float4* hp = (const float4*)(h_seq + (size_t)m * 512 + lane * 8);
  float4 a = hp[0], b2 = hp[1];
  float h[8] = {a.x, a.y, a.z, a.w, b2.x, b2.y, b2.z, b2.w};
#pragma unroll
  for (int k = 0; k < 12; k++) {
    const float4* wp = (const float4*)(W_out + k * 512 + lane * 8);
    float4 w0 = wp[0], w1 = wp[1];
    float w[8] = {w0.x, w0.y, w0.z, w0.w, w1.x, w1.y, w1.z, w1.w};
    float p = 0.0f;
#pragma unroll
    for (int j = 0; j < 8; j++) p += h[j] * w[j];
#pragma unroll
    for (int off = 32; off > 0; off >>= 1) p += __shfl_xor(p, off);
    if (lane == 0) feats[(size_t)m * 12 + k] = p + b_out[k];
  }
}

// ---------------------------------------------------------------------------
// Kernel 4: Viterbi per batch (one wave). First-max tie-break == jnp.argmax.
// out_path written as fp32 tag values.
// ---------------------------------------------------------------------------
__global__ __launch_bounds__(64) void viterbi_k(
    const float* __restrict__ feats, const float* __restrict__ trans,
    float* __restrict__ terminal, int* __restrict__ best,
    float* __restrict__ out_path)
{
  const int b = blockIdx.x;
  const int lane = threadIdx.x;
  __shared__ unsigned char bp[512][12];
  float trow[12];
#pragma unroll
  for (int pv = 0; pv < 12; pv++)
    trow[pv] = (lane < 12) ? trans[lane * 12 + pv] : -10000.0f;
  float fv = (lane == 10) ? 0.0f : -10000.0f;   // START = 10
  for (int t = 0; t < 512; t++) {
    float bestv = -3.4e38f;
    int arg = 0;
#pragma unroll
    for (int pv = 0; pv < 12; pv++) {
      float sc = __shfl(fv, pv) + trow[pv];
      if (sc > bestv) { bestv = sc; arg = pv; }   // strict > keeps first max
    }
    float ft = (lane < 12) ? feats[(size_t)(b * 512 + t) * 12 + lane] : 0.0f;
    if (lane < 12) {
      bp[t][lane] = (unsigned char)arg;
      fv = bestv + ft;                            // emit added after max
    }
  }
  float term = fv + ((lane < 12) ? trans[11 * 12 + lane] : 0.0f);  // STOP = 11
  if (lane < 12) terminal[b * 12 + lane] = term;
  float v = (lane < 12) ? term : -3.4e38f;
  int idx = lane;
#pragma unroll
  for (int off = 8; off > 0; off >>= 1) {
    float ov = __shfl_down(v, off);
    int oi = __shfl_down(idx, off);
    if (ov > v || (ov == v && oi < idx)) { v = ov; idx = oi; }
  }
  int bidx = __shfl(idx, 0);
  __syncthreads();                                // bp writes visible to lane 0
  if (lane == 0) {
    best[b] = bidx;
    int tag = bidx;
    out_path[b * 512 + 511] = (float)bidx;
    for (int t = 511; t >= 1; t--) {
      tag = bp[t][tag];
      out_path[b * 512 + t - 1] = (float)tag;
    }
  }
}

// ---------------------------------------------------------------------------
// Kernel 5: path_score[i][j] = terminal[i][best[j]]  (faithful [B,B] quirk)
// ---------------------------------------------------------------------------
__global__ __launch_bounds__(256) void pscore_k(
    const float* __restrict__ terminal, const int* __restrict__ best,
    float* __restrict__ out)
{
  int idx = blockIdx.x * 256 + threadIdx.x;
  if (idx < 1024) {
    int i = idx >> 5, j = idx & 31;
    out[idx] = terminal[i * 12 + best[j]];
  }
}

// ---------------------------------------------------------------------------
extern "C" void kernel_launch(void* const* d_in, const int* in_sizes, int n_in,
                              void* d_out, int out_size, void* d_ws, size_t ws_size,
                              hipStream_t stream)
{
  const int*   sent  = (const int*)d_in[0];
  const float* embed = (const float*)d_in[1];
  const float* wih_f = (const float*)d_in[2];
  const float* whh_f = (const float*)d_in[3];
  const float* b_f   = (const float*)d_in[4];
  const float* wih_b = (const float*)d_in[5];
  const float* whh_b = (const float*)d_in[6];
  const float* b_b   = (const float*)d_in[7];
  const float* h0    = (const float*)d_in[8];
  const float* c0    = (const float*)d_in[9];
  const float* W_out = (const float*)d_in[10];
  const float* b_out = (const float*)d_in[11];
  const float* trans = (const float*)d_in[12];

  char* ws = (char*)d_ws;
  float* xg    = (float*)(ws);                 // 134217728 B
  float* h_seq = (float*)(ws + 134217728);     //  33554432 B
  float* feats = (float*)(ws + 167772160);     //    786432 B
  float* term  = (float*)(ws + 168693760);     //      1536 B
  int*   best  = (int*)(ws + 168695296);       //       128 B

  float* outp = (float*)d_out;

  xg_simple<<<dim3(256, 32), 256, 0, stream>>>(sent, embed, wih_f, wih_b, b_f, b_b, xg);
  lstm_simple<<<64, 256, 0, stream>>>(xg, whh_f, whh_b, h0, c0, h_seq);
  feats_k<<<4096, 256, 0, stream>>>(h_seq, W_out, b_out, feats);
  viterbi_k<<<32, 64, 0, stream>>>(feats, trans, term, best, outp + 1024);
  pscore_k<<<4, 256, 0, stream>>>(term, best, outp);
}

// Round 6
// 5306.190 us; speedup vs baseline: 3.0858x; 3.0858x over previous
//
#include <hip/hip_runtime.h>
#include <hip/hip_bf16.h>

// BiLSTM-CRF forward: B=32, T=512, E=512, H=256 (per dir), 4H=1024, K=12
// Inputs: fp32 (+ int32 sentence). Outputs fp32:
//   [0,1024)      path_score [32][32]
//   [1024,17408)  best_path  [32][512] (tags as fp32)
// R6: R3's MFMA pipeline (persistent-VGPR w_hh, hi/lo bf16 split, agent-scope
// h exchange) with the R5-discovered fp32 output dtype.

typedef __attribute__((ext_vector_type(8))) __bf16 bf16x8;
typedef __attribute__((ext_vector_type(8))) unsigned short u16x8;
typedef __attribute__((ext_vector_type(4))) float  f32x4;

#define MFMA16(a, b, c) __builtin_amdgcn_mfma_f32_16x16x32_bf16((a), (b), (c), 0, 0, 0)

__device__ __forceinline__ float sigm(float x) { return 1.0f / (1.0f + __expf(-x)); }
__device__ __forceinline__ float tanh_f(float x) {
  x = fminf(fmaxf(x, -15.0f), 15.0f);
  float e = __expf(2.0f * x);
  return (e - 1.0f) / (e + 1.0f);
}

__device__ __forceinline__ void split8(const float* v, bf16x8& hi, bf16x8& lo) {
#pragma unroll
  for (int j = 0; j < 8; j++) {
    __bf16 h = (__bf16)v[j];
    hi[j] = h;
    lo[j] = (__bf16)(v[j] - (float)h);
  }
}

// ---------------------------------------------------------------------------
// Kernel 1: xg[m=(b,t)][n=(dir,gate,unit)] = embed[sent[m]].w_ih[n] + bias[n]
// M=16384, N=2048, K=512. 128x128 tile/WG, 4 waves 2x2, 3-term hi/lo MFMA.
// ---------------------------------------------------------------------------
__global__ __launch_bounds__(256) void xg_gemm(
    const int* __restrict__ sent, const float* __restrict__ embed,
    const float* __restrict__ wih_f, const float* __restrict__ wih_b,
    const float* __restrict__ bias_f, const float* __restrict__ bias_b,
    float* __restrict__ xg)
{
  __shared__ __bf16 Ah[128][40], Al[128][40];  // 32 k + 8 pad
  __shared__ __bf16 Bh[128][40], Bl[128][40];
  __shared__ int toks[128];
  const int tid = threadIdx.x;
  const int m0 = blockIdx.x * 128, n0 = blockIdx.y * 128;
  if (tid < 128) toks[tid] = sent[m0 + tid];
  const int wave = tid >> 6, lane = tid & 63, q = lane >> 4, c = lane & 15;
  const int wy = wave >> 1, wx = wave & 1;
  f32x4 acc[4][4];
  for (int mt = 0; mt < 4; mt++)
    for (int nt = 0; nt < 4; nt++)
      acc[mt][nt] = f32x4{0.0f, 0.0f, 0.0f, 0.0f};
  __syncthreads();

  for (int k0 = 0; k0 < 512; k0 += 32) {
#pragma unroll
    for (int i = 0; i < 2; i++) {
      int ch = tid + (i << 8);
      int r = ch >> 2, kc = ch & 3;
      float tmp[8];
      const float* asrc = embed + (size_t)toks[r] * 512 + k0 + kc * 8;
#pragma unroll
      for (int j = 0; j < 8; j++) tmp[j] = asrc[j];
      bf16x8 hi, lo;
      split8(tmp, hi, lo);
      *(bf16x8*)&Ah[r][kc * 8] = hi;
      *(bf16x8*)&Al[r][kc * 8] = lo;
      int n = n0 + r;
      const float* wsrc = (n < 1024) ? (wih_f + (size_t)n * 512)
                                     : (wih_b + (size_t)(n - 1024) * 512);
#pragma unroll
      for (int j = 0; j < 8; j++) tmp[j] = wsrc[k0 + kc * 8 + j];
      split8(tmp, hi, lo);
      *(bf16x8*)&Bh[r][kc * 8] = hi;
      *(bf16x8*)&Bl[r][kc * 8] = lo;
    }
    __syncthreads();
    bf16x8 ah[4], al[4], bh[4], bl[4];
#pragma unroll
    for (int t4 = 0; t4 < 4; t4++) {
      int ar = wy * 64 + t4 * 16 + c, br = wx * 64 + t4 * 16 + c;
      ah[t4] = *(const bf16x8*)&Ah[ar][q * 8];
      al[t4] = *(const bf16x8*)&Al[ar][q * 8];
      bh[t4] = *(const bf16x8*)&Bh[br][q * 8];
      bl[t4] = *(const bf16x8*)&Bl[br][q * 8];
    }
#pragma unroll
    for (int mt = 0; mt < 4; mt++)
#pragma unroll
      for (int nt = 0; nt < 4; nt++) {
        acc[mt][nt] = MFMA16(ah[mt], bh[nt], acc[mt][nt]);
        acc[mt][nt] = MFMA16(al[mt], bh[nt], acc[mt][nt]);
        acc[mt][nt] = MFMA16(ah[mt], bl[nt], acc[mt][nt]);
      }
    __syncthreads();
  }

#pragma unroll
  for (int nt = 0; nt < 4; nt++) {
    int n = n0 + wx * 64 + nt * 16 + c;
    float bval = (n < 1024) ? bias_f[n] : bias_b[n - 1024];
#pragma unroll
    for (int mt = 0; mt < 4; mt++) {
      int mbase = m0 + wy * 64 + mt * 16 + q * 4;
#pragma unroll
      for (int reg = 0; reg < 4; reg++)
        xg[(size_t)(mbase + reg) * 2048 + n] = acc[mt][nt][reg] + bval;
    }
  }
}

// ---------------------------------------------------------------------------
// Kernel 2: both LSTM recurrences. 8 blocks: blk = d*4 + hs.
// WG owns 64 hidden units (256 gate rows) for ALL 32 batches; w_hh slice
// (hi/lo bf16 of fp32) persistent in VGPRs as MFMA B-frags. h exchanged via
// packed uint32 agent-scope atomics; release/acquire flag per step.
// ---------------------------------------------------------------------------
__global__ __launch_bounds__(256, 1) void lstm_rec(
    const float* __restrict__ xg,
    const float* __restrict__ whh_f, const float* __restrict__ whh_b,
    const float* __restrict__ h0, const float* __restrict__ c0,
    float* __restrict__ h_seq,     // [32][512][512]: cols 0-255 fwd, 256-511 bwd
    unsigned int* __restrict__ hx, // [dir][parity][32][256] packed hi/lo bf16
    int* __restrict__ flags)       // [dir][512]
{
  const int blk = blockIdx.x;
  const int d = blk >> 2, hs = blk & 3;
  const int tid = threadIdx.x;
  const int wave = tid >> 6, lane = tid & 63, q = lane >> 4, c = lane & 15;
  const float* __restrict__ whh = d ? whh_b : whh_f;

  __shared__ __bf16 hfrag[2][16][512];   // [hi/lo][mt*8+ks][xor-swizzled frag]

  bf16x8 wfh[4][8], wfl[4][8];
#pragma unroll
  for (int g = 0; g < 4; g++) {
    int row = g * 256 + hs * 64 + wave * 16 + c;   // w_hh row (gate-major)
    const float* wr = whh + (size_t)row * 256;
#pragma unroll
    for (int ks = 0; ks < 8; ks++) {
      float tmp[8];
#pragma unroll
      for (int j = 0; j < 8; j++) tmp[j] = wr[ks * 32 + q * 8 + j];
      split8(tmp, wfh[g][ks], wfl[g][ks]);
    }
  }
  const int ug = hs * 64 + wave * 16 + c;
  float cst[2][4];
#pragma unroll
  for (int mt = 0; mt < 2; mt++)
#pragma unroll
    for (int reg = 0; reg < 4; reg++)
      cst[mt][reg] = c0[d * 8192 + (mt * 16 + q * 4 + reg) * 256 + ug];

  const int sb = tid >> 3;            // staging: batch row
  const int kc4 = (tid & 7) * 4;      // staging: first 8-elem chunk

  for (int s = 0; s < 512; s++) {
    const int t_seq = d ? (511 - s) : s;
    const int p = s & 1;

    if (s > 0) {
      if (tid == 0) {
        while (__hip_atomic_load(&flags[d * 512 + s - 1], __ATOMIC_ACQUIRE,
                                 __HIP_MEMORY_SCOPE_AGENT) < 4)
          __builtin_amdgcn_s_sleep(2);
      }
      __syncthreads();
    }

    if (s == 0) {
#pragma unroll
      for (int i = 0; i < 4; i++) {
        int kc = kc4 + i;
        float tmp[8];
        const float* src = h0 + d * 8192 + sb * 256 + kc * 8;
#pragma unroll
        for (int j = 0; j < 8; j++) tmp[j] = src[j];
        bf16x8 vhi, vlo;
        split8(tmp, vhi, vlo);
        int fid = ((sb >> 4) << 3) + (kc >> 2);
        int cid = ((kc & 3) << 4) + (sb & 15);
        int pos = cid ^ (fid & 7);
        *(bf16x8*)&hfrag[0][fid][pos * 8] = vhi;
        *(bf16x8*)&hfrag[1][fid][pos * 8] = vlo;
      }
    } else {
      unsigned int vals[4][8];
      const unsigned int* hb = hx + ((size_t)((d * 2 + p) * 32 + sb)) * 256 + kc4 * 8;
#pragma unroll
      for (int i = 0; i < 4; i++)
#pragma unroll
        for (int j = 0; j < 8; j++)
          vals[i][j] = __hip_atomic_load(hb + i * 8 + j, __ATOMIC_RELAXED,
                                         __HIP_MEMORY_SCOPE_AGENT);
#pragma unroll
      for (int i = 0; i < 4; i++) {
        int kc = kc4 + i;
        u16x8 vhi, vlo;
#pragma unroll
        for (int j = 0; j < 8; j++) {
          vhi[j] = (unsigned short)(vals[i][j] >> 16);
          vlo[j] = (unsigned short)(vals[i][j] & 0xffffu);
        }
        int fid = ((sb >> 4) << 3) + (kc >> 2);
        int cid = ((kc & 3) << 4) + (sb & 15);
        int pos = cid ^ (fid & 7);
        *(u16x8*)&hfrag[0][fid][pos * 8] = vhi;
        *(u16x8*)&hfrag[1][fid][pos * 8] = vlo;
      }
    }

    f32x4 acc[2][4];
#pragma unroll
    for (int mt = 0; mt < 2; mt++)
#pragma unroll
      for (int reg = 0; reg < 4; reg++) {
        int b = mt * 16 + q * 4 + reg;
        const float* xr = xg + ((size_t)(b * 512 + t_seq) << 11) + (d << 10) + ug;
#pragma unroll
        for (int g = 0; g < 4; g++)
          acc[mt][g][reg] = xr[g << 8];
      }

    __syncthreads();

#pragma unroll
    for (int ks = 0; ks < 8; ks++) {
      int pos = (lane ^ ks) * 8;
      bf16x8 ahi0 = *(const bf16x8*)&hfrag[0][ks][pos];
      bf16x8 ahi1 = *(const bf16x8*)&hfrag[0][8 + ks][pos];
      bf16x8 alo0 = *(const bf16x8*)&hfrag[1][ks][pos];
      bf16x8 alo1 = *(const bf16x8*)&hfrag[1][8 + ks][pos];
#pragma unroll
      for (int g = 0; g < 4; g++) {
        acc[0][g] = MFMA16(ahi0, wfh[g][ks], acc[0][g]);
        acc[1][g] = MFMA16(ahi1, wfh[g][ks], acc[1][g]);
        acc[0][g] = MFMA16(alo0, wfh[g][ks], acc[0][g]);
        acc[1][g] = MFMA16(alo1, wfh[g][ks], acc[1][g]);
        acc[0][g] = MFMA16(ahi0, wfl[g][ks], acc[0][g]);
        acc[1][g] = MFMA16(ahi1, wfl[g][ks], acc[1][g]);
      }
    }

    const int pn = (s + 1) & 1;
#pragma unroll
    for (int mt = 0; mt < 2; mt++)
#pragma unroll
      for (int reg = 0; reg < 4; reg++) {
        int b = mt * 16 + q * 4 + reg;
        float iv = sigm(acc[mt][0][reg]);
        float fg = sigm(acc[mt][1][reg]);
        float gv = tanh_f(acc[mt][2][reg]);
        float ov = sigm(acc[mt][3][reg]);
        float cn = fg * cst[mt][reg] + iv * gv;
        cst[mt][reg] = cn;
        float hn = ov * tanh_f(cn);
        h_seq[((size_t)(b * 512 + t_seq) << 9) + (d << 8) + ug] = hn;
        __bf16 hhi = (__bf16)hn;
        __bf16 hlo = (__bf16)(hn - (float)hhi);
        unsigned int pack =
            ((unsigned int)__builtin_bit_cast(unsigned short, hhi) << 16) |
            (unsigned int)__builtin_bit_cast(unsigned short, hlo);
        __hip_atomic_store(&hx[((size_t)((d * 2 + pn) * 32 + b)) * 256 + ug], pack,
                           __ATOMIC_RELAXED, __HIP_MEMORY_SCOPE_AGENT);
      }

    __threadfence();
    __syncthreads();
    if (tid == 0)
      __hip_atomic_fetch_add(&flags[d * 512 + s], 1, __ATOMIC_RELEASE,
                             __HIP_MEMORY_SCOPE_AGENT);
  }
}

// ---------------------------------------------------------------------------
// Kernel 3: feats[m][k] = h_seq[m][:] . W_out[k][:] + b_out[k]   (fp32)
// ---------------------------------------------------------------------------
__global__ __launch_bounds__(256) void feats_k(
    const float* __restrict__ h_seq, const float* __restrict__ W_out,
    const float* __restrict__ b_out, float* __restrict__ feats)
{
  int m = blockIdx.x * 4 + (threadIdx.x >> 6);
  int lane = threadIdx.x & 63;
  const float4* hp = (const float4*)(h_seq + (size_t)m * 512 + lane * 8);
  float4 a = hp[0], b2 = hp[1];
  float h[8] = {a.x, a.y, a.z, a.w, b2.x, b2.y, b2.z, b2.w};
#pragma unroll
  for (int k = 0; k < 12; k++) {
    const float4* wp = (const float4*)(W_out + k * 512 + lane * 8);
    float4 w0 = wp[0], w1 = wp[1];
    float w[8] = {w0.x, w0.y, w0.z, w0.w, w1.x, w1.y, w1.z, w1.w};
    float p = 0.0f;
#pragma unroll
    for (int j = 0; j < 8; j++) p += h[j] * w[j];
#pragma unroll
    for (int off = 32; off > 0; off >>= 1) p += __shfl_xor(p, off);
    if (lane == 0) feats[(size_t)m * 12 + k] = p + b_out[k];
  }
}

// ---------------------------------------------------------------------------
// Kernel 4: Viterbi per batch (one wave). First-max tie-break == jnp.argmax.
// ---------------------------------------------------------------------------
__global__ __launch_bounds__(64) void viterbi_k(
    const float* __restrict__ feats, const float* __restrict__ trans,
    float* __restrict__ terminal, int* __restrict__ best,
    float* __restrict__ out_path)
{
  const int b = blockIdx.x;
  const int lane = threadIdx.x;
  __shared__ unsigned char bp[512][12];
  float trow[12];
#pragma unroll
  for (int pv = 0; pv < 12; pv++)
    trow[pv] = (lane < 12) ? trans[lane * 12 + pv] : -10000.0f;
  float fv = (lane == 10) ? 0.0f : -10000.0f;   // START = 10
  for (int t = 0; t < 512; t++) {
    float bestv = -3.4e38f;
    int arg = 0;
#pragma unroll
    for (int pv = 0; pv < 12; pv++) {
      float sc = __shfl(fv, pv) + trow[pv];
      if (sc > bestv) { bestv = sc; arg = pv; }   // strict > keeps first max
    }
    float ft = (lane < 12) ? feats[(size_t)(b * 512 + t) * 12 + lane] : 0.0f;
    if (lane < 12) {
      bp[t][lane] = (unsigned char)arg;
      fv = bestv + ft;
    }
  }
  float term = fv + ((lane < 12) ? trans[11 * 12 + lane] : 0.0f);  // STOP = 11
  if (lane < 12) terminal[b * 12 + lane] = term;
  float v = (lane < 12) ? term : -3.4e38f;
  int idx = lane;
#pragma unroll
  for (int off = 8; off > 0; off >>= 1) {
    float ov = __shfl_down(v, off);
    int oi = __shfl_down(idx, off);
    if (ov > v || (ov == v && oi < idx)) { v = ov; idx = oi; }
  }
  int bidx = __shfl(idx, 0);
  __syncthreads();
  if (lane == 0) {
    best[b] = bidx;
    int tag = bidx;
    out_path[b * 512 + 511] = (float)bidx;
    for (int t = 511; t >= 1; t--) {
      tag = bp[t][tag];
      out_path[b * 512 + t - 1] = (float)tag;
    }
  }
}

// ---------------------------------------------------------------------------
// Kernel 5: path_score[i][j] = terminal[i][best[j]]
// ---------------------------------------------------------------------------
__global__ __launch_bounds__(256) void pscore_k(
    const float* __restrict__ terminal, const int* __restrict__ best,
    float* __restrict__ out)
{
  int idx = blockIdx.x * 256 + threadIdx.x;
  if (idx < 1024) {
    int i = idx >> 5, j = idx & 31;
    out[idx] = terminal[i * 12 + best[j]];
  }
}

// ---------------------------------------------------------------------------
extern "C" void kernel_launch(void* const* d_in, const int* in_sizes, int n_in,
                              void* d_out, int out_size, void* d_ws, size_t ws_size,
                              hipStream_t stream)
{
  const int*   sent  = (const int*)d_in[0];
  const float* embed = (const float*)d_in[1];
  const float* wih_f = (const float*)d_in[2];
  const float* whh_f = (const float*)d_in[3];
  const float* b_f   = (const float*)d_in[4];
  const float* wih_b = (const float*)d_in[5];
  const float* whh_b = (const float*)d_in[6];
  const float* b_b   = (const float*)d_in[7];
  const float* h0    = (const float*)d_in[8];
  const float* c0    = (const float*)d_in[9];
  const float* W_out = (const float*)d_in[10];
  const float* b_out = (const float*)d_in[11];
  const float* trans = (const float*)d_in[12];

  char* ws = (char*)d_ws;
  float*        xg    = (float*)(ws);                    // 134217728 B
  float*        h_seq = (float*)(ws + 134217728);        //  33554432 B
  float*        feats = (float*)(ws + 167772160);        //    786432 B
  unsigned int* hx    = (unsigned int*)(ws + 168558592); //    131072 B
  int*          flags = (int*)(ws + 168689664);          //      4096 B
  float*        term  = (float*)(ws + 168693760);        //      1536 B
  int*          best  = (int*)(ws + 168695296);          //       128 B

  float* outp = (float*)d_out;

  hipMemsetAsync(flags, 0, 2 * 512 * sizeof(int), stream);
  xg_gemm<<<dim3(128, 16), 256, 0, stream>>>(sent, embed, wih_f, wih_b, b_f, b_b, xg);
  lstm_rec<<<8, 256, 0, stream>>>(xg, whh_f, whh_b, h0, c0, h_seq, hx, flags);
  feats_k<<<4096, 256, 0, stream>>>(h_seq, W_out, b_out, feats);
  viterbi_k<<<32, 64, 0, stream>>>(feats, trans, term, best, outp + 1024);
  pscore_k<<<4, 256, 0, stream>>>(term, best, outp);
}

// Round 7
// 4587.140 us; speedup vs baseline: 3.5695x; 1.1568x over previous
//
#include <hip/hip_runtime.h>
#include <hip/hip_bf16.h>

// BiLSTM-CRF forward: B=32, T=512, E=512, H=256 (per dir), 4H=1024, K=12
// Inputs: fp32 (+ int32 sentence). Outputs fp32:
//   [0,1024)      path_score [32][32]
//   [1024,17408)  best_path  [32][512] (tags as fp32)
// R7: lstm_rec sync de-fenced — all-relaxed agent-scope atomics (LLC-point
// ops need no buffer_inv/wbl2; pre-barrier vmcnt(0) drain orders data before
// flag), xg prefetched before the flag poll. Rest identical to R6.

typedef __attribute__((ext_vector_type(8))) __bf16 bf16x8;
typedef __attribute__((ext_vector_type(8))) unsigned short u16x8;
typedef __attribute__((ext_vector_type(4))) float  f32x4;

#define MFMA16(a, b, c) __builtin_amdgcn_mfma_f32_16x16x32_bf16((a), (b), (c), 0, 0, 0)

__device__ __forceinline__ float sigm(float x) { return 1.0f / (1.0f + __expf(-x)); }
__device__ __forceinline__ float tanh_f(float x) {
  x = fminf(fmaxf(x, -15.0f), 15.0f);
  float e = __expf(2.0f * x);
  return (e - 1.0f) / (e + 1.0f);
}

__device__ __forceinline__ void split8(const float* v, bf16x8& hi, bf16x8& lo) {
#pragma unroll
  for (int j = 0; j < 8; j++) {
    __bf16 h = (__bf16)v[j];
    hi[j] = h;
    lo[j] = (__bf16)(v[j] - (float)h);
  }
}

// ---------------------------------------------------------------------------
// Kernel 1: xg[m=(b,t)][n=(dir,gate,unit)] = embed[sent[m]].w_ih[n] + bias[n]
// M=16384, N=2048, K=512. 128x128 tile/WG, 4 waves 2x2, 3-term hi/lo MFMA.
// ---------------------------------------------------------------------------
__global__ __launch_bounds__(256) void xg_gemm(
    const int* __restrict__ sent, const float* __restrict__ embed,
    const float* __restrict__ wih_f, const float* __restrict__ wih_b,
    const float* __restrict__ bias_f, const float* __restrict__ bias_b,
    float* __restrict__ xg)
{
  __shared__ __bf16 Ah[128][40], Al[128][40];  // 32 k + 8 pad
  __shared__ __bf16 Bh[128][40], Bl[128][40];
  __shared__ int toks[128];
  const int tid = threadIdx.x;
  const int m0 = blockIdx.x * 128, n0 = blockIdx.y * 128;
  if (tid < 128) toks[tid] = sent[m0 + tid];
  const int wave = tid >> 6, lane = tid & 63, q = lane >> 4, c = lane & 15;
  const int wy = wave >> 1, wx = wave & 1;
  f32x4 acc[4][4];
  for (int mt = 0; mt < 4; mt++)
    for (int nt = 0; nt < 4; nt++)
      acc[mt][nt] = f32x4{0.0f, 0.0f, 0.0f, 0.0f};
  __syncthreads();

  for (int k0 = 0; k0 < 512; k0 += 32) {
#pragma unroll
    for (int i = 0; i < 2; i++) {
      int ch = tid + (i << 8);
      int r = ch >> 2, kc = ch & 3;
      float tmp[8];
      const float* asrc = embed + (size_t)toks[r] * 512 + k0 + kc * 8;
#pragma unroll
      for (int j = 0; j < 8; j++) tmp[j] = asrc[j];
      bf16x8 hi, lo;
      split8(tmp, hi, lo);
      *(bf16x8*)&Ah[r][kc * 8] = hi;
      *(bf16x8*)&Al[r][kc * 8] = lo;
      int n = n0 + r;
      const float* wsrc = (n < 1024) ? (wih_f + (size_t)n * 512)
                                     : (wih_b + (size_t)(n - 1024) * 512);
#pragma unroll
      for (int j = 0; j < 8; j++) tmp[j] = wsrc[k0 + kc * 8 + j];
      split8(tmp, hi, lo);
      *(bf16x8*)&Bh[r][kc * 8] = hi;
      *(bf16x8*)&Bl[r][kc * 8] = lo;
    }
    __syncthreads();
    bf16x8 ah[4], al[4], bh[4], bl[4];
#pragma unroll
    for (int t4 = 0; t4 < 4; t4++) {
      int ar = wy * 64 + t4 * 16 + c, br = wx * 64 + t4 * 16 + c;
      ah[t4] = *(const bf16x8*)&Ah[ar][q * 8];
      al[t4] = *(const bf16x8*)&Al[ar][q * 8];
      bh[t4] = *(const bf16x8*)&Bh[br][q * 8];
      bl[t4] = *(const bf16x8*)&Bl[br][q * 8];
    }
#pragma unroll
    for (int mt = 0; mt < 4; mt++)
#pragma unroll
      for (int nt = 0; nt < 4; nt++) {
        acc[mt][nt] = MFMA16(ah[mt], bh[nt], acc[mt][nt]);
        acc[mt][nt] = MFMA16(al[mt], bh[nt], acc[mt][nt]);
        acc[mt][nt] = MFMA16(ah[mt], bl[nt], acc[mt][nt]);
      }
    __syncthreads();
  }

#pragma unroll
  for (int nt = 0; nt < 4; nt++) {
    int n = n0 + wx * 64 + nt * 16 + c;
    float bval = (n < 1024) ? bias_f[n] : bias_b[n - 1024];
#pragma unroll
    for (int mt = 0; mt < 4; mt++) {
      int mbase = m0 + wy * 64 + mt * 16 + q * 4;
#pragma unroll
      for (int reg = 0; reg < 4; reg++)
        xg[(size_t)(mbase + reg) * 2048 + n] = acc[mt][nt][reg] + bval;
    }
  }
}

// ---------------------------------------------------------------------------
// Kernel 2: both LSTM recurrences. 8 blocks: blk = d*4 + hs.
// WG owns 64 hidden units (256 gate rows) for ALL 32 batches; w_hh slice
// (hi/lo bf16 of fp32) persistent in VGPRs as MFMA B-frags. h exchanged via
// packed uint32 agent-scope RELAXED atomics (LLC coherence point); ordering
// from the pre-barrier vmcnt(0) drain. No fences (no buffer_inv/wbl2).
// ---------------------------------------------------------------------------
__global__ __launch_bounds__(256, 1) void lstm_rec(
    const float* __restrict__ xg,
    const float* __restrict__ whh_f, const float* __restrict__ whh_b,
    const float* __restrict__ h0, const float* __restrict__ c0,
    float* __restrict__ h_seq,     // [32][512][512]: cols 0-255 fwd, 256-511 bwd
    unsigned int* __restrict__ hx, // [dir][parity][32][256] packed hi/lo bf16
    int* __restrict__ flags)       // [dir][512]
{
  const int blk = blockIdx.x;
  const int d = blk >> 2, hs = blk & 3;
  const int tid = threadIdx.x;
  const int wave = tid >> 6, lane = tid & 63, q = lane >> 4, c = lane & 15;
  const float* __restrict__ whh = d ? whh_b : whh_f;

  __shared__ __bf16 hfrag[2][16][512];   // [hi/lo][mt*8+ks][xor-swizzled frag]

  bf16x8 wfh[4][8], wfl[4][8];
#pragma unroll
  for (int g = 0; g < 4; g++) {
    int row = g * 256 + hs * 64 + wave * 16 + c;   // w_hh row (gate-major)
    const float* wr = whh + (size_t)row * 256;
#pragma unroll
    for (int ks = 0; ks < 8; ks++) {
      float tmp[8];
#pragma unroll
      for (int j = 0; j < 8; j++) tmp[j] = wr[ks * 32 + q * 8 + j];
      split8(tmp, wfh[g][ks], wfl[g][ks]);
    }
  }
  const int ug = hs * 64 + wave * 16 + c;
  float cst[2][4];
#pragma unroll
  for (int mt = 0; mt < 2; mt++)
#pragma unroll
    for (int reg = 0; reg < 4; reg++)
      cst[mt][reg] = c0[d * 8192 + (mt * 16 + q * 4 + reg) * 256 + ug];

  const int sb = tid >> 3;            // staging: batch row
  const int kc4 = (tid & 7) * 4;      // staging: first 8-elem chunk

  for (int s = 0; s < 512; s++) {
    const int t_seq = d ? (511 - s) : s;
    const int p = s & 1;

    // prefetch xg for this step (flag-independent): loads fly during the poll
    float xv[2][4][4];
#pragma unroll
    for (int mt = 0; mt < 2; mt++)
#pragma unroll
      for (int reg = 0; reg < 4; reg++) {
        int b = mt * 16 + q * 4 + reg;
        const float* xr = xg + ((size_t)(b * 512 + t_seq) << 11) + (d << 10) + ug;
#pragma unroll
        for (int g = 0; g < 4; g++)
          xv[mt][g][reg] = xr[g << 8];
      }

    if (s > 0) {
      if (tid == 0) {
        while (__hip_atomic_load(&flags[d * 512 + s - 1], __ATOMIC_RELAXED,
                                 __HIP_MEMORY_SCOPE_AGENT) < 4)
          __builtin_amdgcn_s_sleep(1);
      }
      __syncthreads();
    }

    if (s == 0) {
#pragma unroll
      for (int i = 0; i < 4; i++) {
        int kc = kc4 + i;
        float tmp[8];
        const float* src = h0 + d * 8192 + sb * 256 + kc * 8;
#pragma unroll
        for (int j = 0; j < 8; j++) tmp[j] = src[j];
        bf16x8 vhi, vlo;
        split8(tmp, vhi, vlo);
        int fid = ((sb >> 4) << 3) + (kc >> 2);
        int cid = ((kc & 3) << 4) + (sb & 15);
        int pos = cid ^ (fid & 7);
        *(bf16x8*)&hfrag[0][fid][pos * 8] = vhi;
        *(bf16x8*)&hfrag[1][fid][pos * 8] = vlo;
      }
    } else {
      unsigned int vals[4][8];
      const unsigned int* hb = hx + ((size_t)((d * 2 + p) * 32 + sb)) * 256 + kc4 * 8;
#pragma unroll
      for (int i = 0; i < 4; i++)
#pragma unroll
        for (int j = 0; j < 8; j++)
          vals[i][j] = __hip_atomic_load(hb + i * 8 + j, __ATOMIC_RELAXED,
                                         __HIP_MEMORY_SCOPE_AGENT);
#pragma unroll
      for (int i = 0; i < 4; i++) {
        int kc = kc4 + i;
        u16x8 vhi, vlo;
#pragma unroll
        for (int j = 0; j < 8; j++) {
          vhi[j] = (unsigned short)(vals[i][j] >> 16);
          vlo[j] = (unsigned short)(vals[i][j] & 0xffffu);
        }
        int fid = ((sb >> 4) << 3) + (kc >> 2);
        int cid = ((kc & 3) << 4) + (sb & 15);
        int pos = cid ^ (fid & 7);
        *(u16x8*)&hfrag[0][fid][pos * 8] = vhi;
        *(u16x8*)&hfrag[1][fid][pos * 8] = vlo;
      }
    }

    f32x4 acc[2][4];
#pragma unroll
    for (int mt = 0; mt < 2; mt++)
#pragma unroll
      for (int g = 0; g < 4; g++)
#pragma unroll
        for (int reg = 0; reg < 4; reg++)
          acc[mt][g][reg] = xv[mt][g][reg];

    __syncthreads();

#pragma unroll
    for (int ks = 0; ks < 8; ks++) {
      int pos = (lane ^ ks) * 8;
      bf16x8 ahi0 = *(const bf16x8*)&hfrag[0][ks][pos];
      bf16x8 ahi1 = *(const bf16x8*)&hfrag[0][8 + ks][pos];
      bf16x8 alo0 = *(const bf16x8*)&hfrag[1][ks][pos];
      bf16x8 alo1 = *(const bf16x8*)&hfrag[1][8 + ks][pos];
#pragma unroll
      for (int g = 0; g < 4; g++) {
        acc[0][g] = MFMA16(ahi0, wfh[g][ks], acc[0][g]);
        acc[1][g] = MFMA16(ahi1, wfh[g][ks], acc[1][g]);
        acc[0][g] = MFMA16(alo0, wfh[g][ks], acc[0][g]);
        acc[1][g] = MFMA16(alo1, wfh[g][ks], acc[1][g]);
        acc[0][g] = MFMA16(ahi0, wfl[g][ks], acc[0][g]);
        acc[1][g] = MFMA16(ahi1, wfl[g][ks], acc[1][g]);
      }
    }

    const int pn = (s + 1) & 1;
#pragma unroll
    for (int mt = 0; mt < 2; mt++)
#pragma unroll
      for (int reg = 0; reg < 4; reg++) {
        int b = mt * 16 + q * 4 + reg;
        float iv = sigm(acc[mt][0][reg]);
        float fg = sigm(acc[mt][1][reg]);
        float gv = tanh_f(acc[mt][2][reg]);
        float ov = sigm(acc[mt][3][reg]);
        float cn = fg * cst[mt][reg] + iv * gv;
        cst[mt][reg] = cn;
        float hn = ov * tanh_f(cn);
        h_seq[((size_t)(b * 512 + t_seq) << 9) + (d << 8) + ug] = hn;
        __bf16 hhi = (__bf16)hn;
        __bf16 hlo = (__bf16)(hn - (float)hhi);
        unsigned int pack =
            ((unsigned int)__builtin_bit_cast(unsigned short, hhi) << 16) |
            (unsigned int)__builtin_bit_cast(unsigned short, hlo);
        __hip_atomic_store(&hx[((size_t)((d * 2 + pn) * 32 + b)) * 256 + ug], pack,
                           __ATOMIC_RELAXED, __HIP_MEMORY_SCOPE_AGENT);
      }

    // pre-barrier vmcnt(0) drains the hx stores to the LLC; flag add after.
    __syncthreads();
    if (tid == 0)
      __hip_atomic_fetch_add(&flags[d * 512 + s], 1, __ATOMIC_RELAXED,
                             __HIP_MEMORY_SCOPE_AGENT);
  }
}

// ---------------------------------------------------------------------------
// Kernel 3: feats[m][k] = h_seq[m][:] . W_out[k][:] + b_out[k]   (fp32)
// ---------------------------------------------------------------------------
__global__ __launch_bounds__(256) void feats_k(
    const float* __restrict__ h_seq, const float* __restrict__ W_out,
    const float* __restrict__ b_out, float* __restrict__ feats)
{
  int m = blockIdx.x * 4 + (threadIdx.x >> 6);
  int lane = threadIdx.x & 63;
  const float4* hp = (const float4*)(h_seq + (size_t)m * 512 + lane * 8);
  float4 a = hp[0], b2 = hp[1];
  float h[8] = {a.x, a.y, a.z, a.w, b2.x, b2.y, b2.z, b2.w};
#pragma unroll
  for (int k = 0; k < 12; k++) {
    const float4* wp = (const float4*)(W_out + k * 512 + lane * 8);
    float4 w0 = wp[0], w1 = wp[1];
    float w[8] = {w0.x, w0.y, w0.z, w0.w, w1.x, w1.y, w1.z, w1.w};
    float p = 0.0f;
#pragma unroll
    for (int j = 0; j < 8; j++) p += h[j] * w[j];
#pragma unroll
    for (int off = 32; off > 0; off >>= 1) p += __shfl_xor(p, off);
    if (lane == 0) feats[(size_t)m * 12 + k] = p + b_out[k];
  }
}

// ---------------------------------------------------------------------------
// Kernel 4: Viterbi per batch (one wave). First-max tie-break == jnp.argmax.
// ---------------------------------------------------------------------------
__global__ __launch_bounds__(64) void viterbi_k(
    const float* __restrict__ feats, const float* __restrict__ trans,
    float* __restrict__ terminal, int* __restrict__ best,
    float* __restrict__ out_path)
{
  const int b = blockIdx.x;
  const int lane = threadIdx.x;
  __shared__ unsigned char bp[512][12];
  float trow[12];
#pragma unroll
  for (int pv = 0; pv < 12; pv++)
    trow[pv] = (lane < 12) ? trans[lane * 12 + pv] : -10000.0f;
  float fv = (lane == 10) ? 0.0f : -10000.0f;   // START = 10
  for (int t = 0; t < 512; t++) {
    float bestv = -3.4e38f;
    int arg = 0;
#pragma unroll
    for (int pv = 0; pv < 12; pv++) {
      float sc = __shfl(fv, pv) + trow[pv];
      if (sc > bestv) { bestv = sc; arg = pv; }   // strict > keeps first max
    }
    float ft = (lane < 12) ? feats[(size_t)(b * 512 + t) * 12 + lane] : 0.0f;
    if (lane < 12) {
      bp[t][lane] = (unsigned char)arg;
      fv = bestv + ft;
    }
  }
  float term = fv + ((lane < 12) ? trans[11 * 12 + lane] : 0.0f);  // STOP = 11
  if (lane < 12) terminal[b * 12 + lane] = term;
  float v = (lane < 12) ? term : -3.4e38f;
  int idx = lane;
#pragma unroll
  for (int off = 8; off > 0; off >>= 1) {
    float ov = __shfl_down(v, off);
    int oi = __shfl_down(idx, off);
    if (ov > v || (ov == v && oi < idx)) { v = ov; idx = oi; }
  }
  int bidx = __shfl(idx, 0);
  __syncthreads();
  if (lane == 0) {
    best[b] = bidx;
    int tag = bidx;
    out_path[b * 512 + 511] = (float)bidx;
    for (int t = 511; t >= 1; t--) {
      tag = bp[t][tag];
      out_path[b * 512 + t - 1] = (float)tag;
    }
  }
}

// ---------------------------------------------------------------------------
// Kernel 5: path_score[i][j] = terminal[i][best[j]]
// ---------------------------------------------------------------------------
__global__ __launch_bounds__(256) void pscore_k(
    const float* __restrict__ terminal, const int* __restrict__ best,
    float* __restrict__ out)
{
  int idx = blockIdx.x * 256 + threadIdx.x;
  if (idx < 1024) {
    int i = idx >> 5, j = idx & 31;
    out[idx] = terminal[i * 12 + best[j]];
  }
}

// ---------------------------------------------------------------------------
extern "C" void kernel_launch(void* const* d_in, const int* in_sizes, int n_in,
                              void* d_out, int out_size, void* d_ws, size_t ws_size,
                              hipStream_t stream)
{
  const int*   sent  = (const int*)d_in[0];
  const float* embed = (const float*)d_in[1];
  const float* wih_f = (const float*)d_in[2];
  const float* whh_f = (const float*)d_in[3];
  const float* b_f   = (const float*)d_in[4];
  const float* wih_b = (const float*)d_in[5];
  const float* whh_b = (const float*)d_in[6];
  const float* b_b   = (const float*)d_in[7];
  const float* h0    = (const float*)d_in[8];
  const float* c0    = (const float*)d_in[9];
  const float* W_out = (const float*)d_in[10];
  const float* b_out = (const float*)d_in[11];
  const float* trans = (const float*)d_in[12];

  char* ws = (char*)d_ws;
  float*        xg    = (float*)(ws);                    // 134217728 B
  float*        h_seq = (float*)(ws + 134217728);        //  33554432 B
  float*        feats = (float*)(ws + 167772160);        //    786432 B
  unsigned int* hx    = (unsigned int*)(ws + 168558592); //    131072 B
  int*          flags = (int*)(ws + 168689664);          //      4096 B
  float*        term  = (float*)(ws + 168693760);        //      1536 B
  int*          best  = (int*)(ws + 168695296);          //       128 B

  float* outp = (float*)d_out;

  hipMemsetAsync(flags, 0, 2 * 512 * sizeof(int), stream);
  xg_gemm<<<dim3(128, 16), 256, 0, stream>>>(sent, embed, wih_f, wih_b, b_f, b_b, xg);
  lstm_rec<<<8, 256, 0, stream>>>(xg, whh_f, whh_b, h0, c0, h_seq, hx, flags);
  feats_k<<<4096, 256, 0, stream>>>(h_seq, W_out, b_out, feats);
  viterbi_k<<<32, 64, 0, stream>>>(feats, trans, term, best, outp + 1024);
  pscore_k<<<4, 256, 0, stream>>>(term, best, outp);
}